// Round 7
// baseline (5716.043 us; speedup 1.0000x reference)
//
#include <hip/hip_runtime.h>

// VQ-VAE VectorQuantizer forward, fp32, MI355X.
// B=64, C=D=64, H=W=32 -> N=65536 pixels, K=1024 codes.
// Outputs (flat concat): [0] loss, [1..4194305) quantized BCHW, [4194305..) indices (as float)
//
// R7: LDS-broadcast e (R6 idea) at 1 px/lane so registers FIT.
// R6 lesson: 2 px/lane (128 VGPR of xr) + asm keep-alive anchors + 128-VGPR
// allocator choice = forced scratch spill (WRITE_SIZE 4.9GB, 2.4ms). Anchors
// are only safe when demand < cap. Now: xr[64] + 8 chains + 2xfloat4 staging
// + 4-code-half e-temps ~= 110 VGPR < 128 cap (launch_bounds 512,4).
// e path: per-wave double-buffered LDS (2KB groups), coalesced float4 global
// loads (T14 split: load g+2 issued before compute g, ds_write after), e
// consumed via uniform-address ds_read_b128 broadcasts (conflict-free).
// Per-code arithmetic BIT-IDENTICAL to R0-R6 (passed, absmax 3.8e-6):
// pairwise-8 x_sq (fp-contract off), sequential d-ascending fp32 FMA dot,
// dist = (x_sq - 2*dot) + e_sq, strict-< ascending-k argmin, ascending-chunk merge.

#define KCODES 1024
#define DDIM   64
#define NPIX   65536        // B*H*W
#define QELEMS 4194304      // B*C*H*W
#define IDX_OFF (1 + QELEMS)
#define NWAVE  8            // waves per block = K chunks
#define CHUNK  (KCODES / NWAVE)   // 128 codes per wave
#define NGROUP (CHUNK / 8)  // 16 8-code groups per wave

// ---------------- e_sq precompute: replicate np.sum(e*e, axis=1) pairwise-8 ----------------
__global__ void __launch_bounds__(256) esq_kernel(const float* __restrict__ e,
                                                  float* __restrict__ esq) {
    int k = blockIdx.x * 256 + threadIdx.x;
    if (k >= KCODES) return;
    {
#pragma clang fp contract(off)
        const float* row = e + k * DDIM;
        float r[8];
#pragma unroll
        for (int j = 0; j < 8; ++j) r[j] = row[j] * row[j];
#pragma unroll
        for (int i = 1; i < 8; ++i) {
#pragma unroll
            for (int j = 0; j < 8; ++j) {
                float v = row[i * 8 + j];
                r[j] += v * v;
            }
        }
        esq[k] = ((r[0] + r[1]) + (r[2] + r[3])) + ((r[4] + r[5]) + (r[6] + r[7]));
    }
}

// x_sq helper: EXACT replication of numpy pairwise-8 (no fp contraction)
__device__ __forceinline__ float xsq_pairwise8(const float* xr) {
#pragma clang fp contract(off)
    float r[8];
#pragma unroll
    for (int j = 0; j < 8; ++j) r[j] = xr[j] * xr[j];
#pragma unroll
    for (int ii = 1; ii < 8; ++ii) {
#pragma unroll
        for (int j = 0; j < 8; ++j) {
            float v = xr[ii * 8 + j];
            r[j] += v * v;
        }
    }
    return ((r[0] + r[1]) + (r[2] + r[3])) + ((r[4] + r[5]) + (r[6] + r[7]));
}

// ---------------- main distance + argmin kernel (K-split, 1 px/lane, LDS e) ----------------
// Block = 512 threads = 8 waves. Wave w handles codes [w*128, w*128+128) for the
// block's 64 pixels: lane l owns pixel blk*64+l. No intra-k-loop barriers
// (each wave owns its private double-buffered LDS slot).
__global__ void __launch_bounds__(512, 4) argmin_kernel(const float* __restrict__ x,
                                                        const float* __restrict__ e,
                                                        const float* __restrict__ esq,
                                                        int* __restrict__ idx_out,
                                                        float* __restrict__ out) {
    // per-wave double-buffered e staging: 8 codes x 64 floats = 2KB per buffer
    __shared__ float se[NWAVE][2][512];
    __shared__ float sbest[NWAVE][64];
    __shared__ int   sidx[NWAVE][64];

    const int w = __builtin_amdgcn_readfirstlane(threadIdx.x >> 6);
    const int l = threadIdx.x & 63;
    const int i = blockIdx.x * 64 + l;       // pixel id
    const int b = i >> 10;
    const int p = i & 1023;

    // x[b][d][p], d-stride = 1024 floats; lanes -> 64 consecutive p (coalesced)
    const float* xb = x + (size_t)b * 65536 + p;
    float xr[DDIM];
#pragma unroll
    for (int d = 0; d < DDIM; ++d) xr[d] = xb[(size_t)d * 1024];
    // keep-alive anchors (safe now: total demand ~110 VGPR < 128 cap)
#pragma unroll
    for (int d = 0; d < DDIM; ++d) asm volatile("" : "+v"(xr[d]));

    const float xsq = xsq_pairwise8(xr);

    const int kbeg = w * CHUNK;              // uniform (SGPR)

    // staging: lane l covers 16B slices of the 2KB group (8 codes x 256B row-major)
    float4 st0, st1;
    auto LD = [&](int g) {
        const float* gp = e + (size_t)(kbeg + g * 8) * DDIM;
        st0 = *(const float4*)(gp + 4 * l);          // codes 0-3 of group
        st1 = *(const float4*)(gp + 256 + 4 * l);    // codes 4-7 of group
    };
    auto ST = [&](int parity) {
        *(float4*)&se[w][parity][4 * l] = st0;
        *(float4*)&se[w][parity][256 + 4 * l] = st1;
    };

    LD(0); ST(0);       // group 0 staged
    LD(1);              // group 1 in registers (LDS-written after compute(0))

    float best = 3.4e38f;
    int bidx = 0;

#pragma unroll 1
    for (int g = 0; g < NGROUP; ++g) {
        const int k = kbeg + g * 8;
        const float* eb = &se[w][g & 1][0];

        float a0 = 0.f, a1 = 0.f, a2 = 0.f, a3 = 0.f;
        float a4 = 0.f, a5 = 0.f, a6 = 0.f, a7 = 0.f;
        // d-quads; two 4-code halves per quad to cap live e-temps at 16 VGPRs.
        // Chain order per code stays exactly d-ascending (d = 4q + j).
#pragma unroll
        for (int q = 0; q < 16; ++q) {
            const float x0 = xr[4 * q + 0], x1 = xr[4 * q + 1];
            const float x2 = xr[4 * q + 2], x3 = xr[4 * q + 3];
            {
                const float4 e0 = *(const float4*)&eb[0 * 64 + 4 * q];
                const float4 e1 = *(const float4*)&eb[1 * 64 + 4 * q];
                const float4 e2 = *(const float4*)&eb[2 * 64 + 4 * q];
                const float4 e3 = *(const float4*)&eb[3 * 64 + 4 * q];
                a0 = __builtin_fmaf(x0, e0.x, a0); a0 = __builtin_fmaf(x1, e0.y, a0); a0 = __builtin_fmaf(x2, e0.z, a0); a0 = __builtin_fmaf(x3, e0.w, a0);
                a1 = __builtin_fmaf(x0, e1.x, a1); a1 = __builtin_fmaf(x1, e1.y, a1); a1 = __builtin_fmaf(x2, e1.z, a1); a1 = __builtin_fmaf(x3, e1.w, a1);
                a2 = __builtin_fmaf(x0, e2.x, a2); a2 = __builtin_fmaf(x1, e2.y, a2); a2 = __builtin_fmaf(x2, e2.z, a2); a2 = __builtin_fmaf(x3, e2.w, a2);
                a3 = __builtin_fmaf(x0, e3.x, a3); a3 = __builtin_fmaf(x1, e3.y, a3); a3 = __builtin_fmaf(x2, e3.z, a3); a3 = __builtin_fmaf(x3, e3.w, a3);
            }
            {
                const float4 e4 = *(const float4*)&eb[4 * 64 + 4 * q];
                const float4 e5 = *(const float4*)&eb[5 * 64 + 4 * q];
                const float4 e6 = *(const float4*)&eb[6 * 64 + 4 * q];
                const float4 e7 = *(const float4*)&eb[7 * 64 + 4 * q];
                a4 = __builtin_fmaf(x0, e4.x, a4); a4 = __builtin_fmaf(x1, e4.y, a4); a4 = __builtin_fmaf(x2, e4.z, a4); a4 = __builtin_fmaf(x3, e4.w, a4);
                a5 = __builtin_fmaf(x0, e5.x, a5); a5 = __builtin_fmaf(x1, e5.y, a5); a5 = __builtin_fmaf(x2, e5.z, a5); a5 = __builtin_fmaf(x3, e5.w, a5);
                a6 = __builtin_fmaf(x0, e6.x, a6); a6 = __builtin_fmaf(x1, e6.y, a6); a6 = __builtin_fmaf(x2, e6.z, a6); a6 = __builtin_fmaf(x3, e6.w, a6);
                a7 = __builtin_fmaf(x0, e7.x, a7); a7 = __builtin_fmaf(x1, e7.y, a7); a7 = __builtin_fmaf(x2, e7.z, a7); a7 = __builtin_fmaf(x3, e7.w, a7);
            }
        }

        // dist = (x_sq - 2*dot) + e_sq   (same association as np; /64 exact-monotone, skipped)
        const float q0 = esq[k + 0], q1 = esq[k + 1], q2 = esq[k + 2], q3 = esq[k + 3];
        const float q4 = esq[k + 4], q5 = esq[k + 5], q6 = esq[k + 6], q7 = esq[k + 7];
        float s0 = (xsq - 2.0f * a0) + q0;
        float s1 = (xsq - 2.0f * a1) + q1;
        float s2 = (xsq - 2.0f * a2) + q2;
        float s3 = (xsq - 2.0f * a3) + q3;
        float s4 = (xsq - 2.0f * a4) + q4;
        float s5 = (xsq - 2.0f * a5) + q5;
        float s6 = (xsq - 2.0f * a6) + q6;
        float s7 = (xsq - 2.0f * a7) + q7;
        // strict < , ascending k => first-occurrence min within chunk
        if (s0 < best) { best = s0; bidx = k + 0; }
        if (s1 < best) { best = s1; bidx = k + 1; }
        if (s2 < best) { best = s2; bidx = k + 2; }
        if (s3 < best) { best = s3; bidx = k + 3; }
        if (s4 < best) { best = s4; bidx = k + 4; }
        if (s5 < best) { best = s5; bidx = k + 5; }
        if (s6 < best) { best = s6; bidx = k + 6; }
        if (s7 < best) { best = s7; bidx = k + 7; }

        // T14 async-split tail: LDS-write the prefetched group (vmcnt wait lands
        // here, after ~1200cyc of compute), then issue the next global load.
        if (g + 1 < NGROUP) {
            ST((g + 1) & 1);
            if (g + 2 < NGROUP) LD(g + 2);
        }
    }

    // merge the 8 chunk results: ascending chunk + strict '<' == global first-min
    sbest[w][l] = best;
    sidx[w][l] = bidx;
    __syncthreads();
    if (threadIdx.x < 64) {
        float bb = sbest[0][l];
        int bi = sidx[0][l];
#pragma unroll
        for (int c = 1; c < NWAVE; ++c) {
            float v = sbest[c][l];
            if (v < bb) { bb = v; bi = sidx[c][l]; }
        }
        idx_out[i] = bi;
        out[IDX_OFF + i] = (float)bi;   // harness reads d_out as float32
    }
}

// ---------------- gather + transpose + per-block loss partials ----------------
// block = one (b,d) plane of 1024 pixels; coalesced read/write.
__global__ void __launch_bounds__(256) gather_kernel(const float* __restrict__ x,
                                                     const float* __restrict__ e,
                                                     const int* __restrict__ idx,
                                                     float* __restrict__ out,
                                                     float* __restrict__ partial) {
    const int bd = blockIdx.x;          // = b*64 + d
    const int b = bd >> 6;
    const int d = bd & 63;
    const size_t base = (size_t)bd * 1024;
    const int* idxb = idx + b * 1024;

    float acc = 0.f;
#pragma unroll
    for (int j = 0; j < 4; ++j) {
        int p = threadIdx.x + j * 256;
        int k = idxb[p];
        float ev = e[k * 64 + d];
        float xv = x[base + p];
        out[1 + base + p] = ev;         // quantized (straight-through == codebook value)
        float df = ev - xv;
        acc = __builtin_fmaf(df, df, acc);
    }
    __shared__ float sm[256];
    sm[threadIdx.x] = acc;
    __syncthreads();
    for (int s = 128; s > 0; s >>= 1) {
        if (threadIdx.x < s) sm[threadIdx.x] += sm[threadIdx.x + s];
        __syncthreads();
    }
    if (threadIdx.x == 0) partial[bd] = sm[0];
}

// ---------------- deterministic loss finalize ----------------
__global__ void __launch_bounds__(256) loss_kernel(const float* __restrict__ partial,
                                                   float* __restrict__ out) {
    float acc = 0.f;
    for (int i = threadIdx.x; i < 4096; i += 256) acc += partial[i];
    __shared__ float sm[256];
    sm[threadIdx.x] = acc;
    __syncthreads();
    for (int s = 128; s > 0; s >>= 1) {
        if (threadIdx.x < s) sm[threadIdx.x] += sm[threadIdx.x + s];
        __syncthreads();
    }
    // loss = q_latent + 0.25*e_latent = 1.25 * mean(diff^2)
    if (threadIdx.x == 0) out[0] = sm[0] * (1.25f / 4194304.f);
}

extern "C" void kernel_launch(void* const* d_in, const int* in_sizes, int n_in,
                              void* d_out, int out_size, void* d_ws, size_t ws_size,
                              hipStream_t stream) {
    const float* x = (const float*)d_in[0];   // [64,64,32,32]
    const float* e = (const float*)d_in[1];   // [1024,64]
    float* out = (float*)d_out;

    // ws: [0,4KB) e_sq | [4KB, 4KB+256KB) idx int32 | then 16KB partials
    float* esq = (float*)d_ws;
    int* idx = (int*)((char*)d_ws + 4096);
    float* partial = (float*)((char*)d_ws + 4096 + NPIX * 4);

    esq_kernel<<<4, 256, 0, stream>>>(e, esq);
    argmin_kernel<<<NPIX / 64, 512, 0, stream>>>(x, e, esq, idx, out);
    gather_kernel<<<4096, 256, 0, stream>>>(x, e, idx, out, partial);
    loss_kernel<<<1, 256, 0, stream>>>(partial, out);
}

// Round 8
// 487.495 us; speedup vs baseline: 11.7253x; 11.7253x over previous
//
#include <hip/hip_runtime.h>

// VQ-VAE VectorQuantizer forward, fp32, MI355X.
// B=64, C=D=64, H=W=32 -> N=65536 pixels, K=1024 codes.
// Outputs (flat concat): [0] loss, [1..4194305) quantized BCHW, [4194305..) indices (as float)
//
// R8: x tile in LDS (not registers), e on the VMEM counter.
// R4/R6/R7 lesson: the allocator will NOT keep xr[64] live across the k-loop
// (remat at best, scratch-spill catastrophe with anchors: R7 = 22GB HBM).
// Fix: x[64px][64d] = 16KB staged once per block in LDS, shared by all 8
// waves; lane reads x_lds[d][l] = one vaddr + imm offsets (zero addr VALU,
// 2-way bank = free). e loads forced onto VMEM via opaque v0=0 address
// (uniform s_load would share lgkmcnt with the x ds_reads; DS+SMEM complete
// out-of-order -> lgkmcnt(0) drains would serialize). e is L2-resident
// (256KB); same-address wave loads broadcast from one line; vmcnt pipelines.
// Per-code arithmetic BIT-IDENTICAL to R0-R7 (passed, absmax 3.8e-6):
// pairwise-8 x_sq (fp-contract off), sequential d-ascending fp32 FMA dot,
// dist = (x_sq - 2*dot) + e_sq, strict-< ascending-k argmin, ascending-chunk merge.

#define KCODES 1024
#define DDIM   64
#define NPIX   65536        // B*H*W
#define QELEMS 4194304      // B*C*H*W
#define IDX_OFF (1 + QELEMS)
#define NWAVE  8            // waves per block = K chunks
#define CHUNK  (KCODES / NWAVE)   // 128 codes per wave
#define NGROUP (CHUNK / 8)  // 16 8-code groups per wave

// ---------------- e_sq precompute: replicate np.sum(e*e, axis=1) pairwise-8 ----------------
__global__ void __launch_bounds__(256) esq_kernel(const float* __restrict__ e,
                                                  float* __restrict__ esq) {
    int k = blockIdx.x * 256 + threadIdx.x;
    if (k >= KCODES) return;
    {
#pragma clang fp contract(off)
        const float* row = e + k * DDIM;
        float r[8];
#pragma unroll
        for (int j = 0; j < 8; ++j) r[j] = row[j] * row[j];
#pragma unroll
        for (int i = 1; i < 8; ++i) {
#pragma unroll
            for (int j = 0; j < 8; ++j) {
                float v = row[i * 8 + j];
                r[j] += v * v;
            }
        }
        esq[k] = ((r[0] + r[1]) + (r[2] + r[3])) + ((r[4] + r[5]) + (r[6] + r[7]));
    }
}

// ---------------- main distance + argmin kernel (K-split, x in LDS, e via VMEM) ----------------
// Block = 512 threads = 8 waves; 64 pixels/block. Wave w: codes [w*128, w*128+128).
__global__ void __launch_bounds__(512, 4) argmin_kernel(const float* __restrict__ x,
                                                        const float* __restrict__ e,
                                                        const float* __restrict__ esq,
                                                        int* __restrict__ idx_out,
                                                        float* __restrict__ out) {
    __shared__ float x_lds[DDIM][64];    // [d][l], 16KB; read addr = l*4 + d*256 (imm)
    __shared__ float sbest[NWAVE][64];
    __shared__ int   sidx[NWAVE][64];

    const int w = __builtin_amdgcn_readfirstlane(threadIdx.x >> 6);
    const int l = threadIdx.x & 63;
    const int pix = blockIdx.x * 64 + l;     // this lane's pixel
    const int b = (blockIdx.x * 64) >> 10;   // same b for whole block (64-aligned)
    const int p0 = (blockIdx.x * 64) & 1023;

    // stage x tile: 64 d-rows x 64 px, coalesced 256B segments
    {
        const float* xg = x + (size_t)b * 65536 + p0;
        for (int t = threadIdx.x; t < DDIM * 64; t += 512)
            x_lds[t >> 6][t & 63] = xg[(size_t)(t >> 6) * 1024 + (t & 63)];
    }
    __syncthreads();

    // x_sq: EXACT numpy pairwise-8 (rounded products, no contraction), from LDS
    float xsq;
    {
#pragma clang fp contract(off)
        float r[8];
#pragma unroll
        for (int j = 0; j < 8; ++j) { float v = x_lds[j][l]; r[j] = v * v; }
#pragma unroll
        for (int ii = 1; ii < 8; ++ii) {
#pragma unroll
            for (int j = 0; j < 8; ++j) { float v = x_lds[ii * 8 + j][l]; r[j] += v * v; }
        }
        xsq = ((r[0] + r[1]) + (r[2] + r[3])) + ((r[4] + r[5]) + (r[6] + r[7]));
    }

    // opaque per-lane zero: makes e addresses divergence-opaque so the compiler
    // emits global_load (vmcnt) instead of s_load (lgkmcnt, would mix with DS).
    int vzero;
    asm("v_mov_b32 %0, 0" : "=v"(vzero));

    float best = 3.4e38f;
    int bidx = 0;
    const int kbeg = w * CHUNK;              // uniform (SGPR)

#pragma unroll 1
    for (int g = 0; g < NGROUP; ++g) {
        const int k = kbeg + g * 8;
        const float* eg = e + (size_t)k * DDIM + vzero;   // VMEM base (per-group)

        float a0 = 0.f, a1 = 0.f, a2 = 0.f, a3 = 0.f;
        float a4 = 0.f, a5 = 0.f, a6 = 0.f, a7 = 0.f;
        // d-quads; per code the chain stays exactly d-ascending (d = 4q + j).
#pragma unroll
        for (int q = 0; q < 16; ++q) {
            const float4 e0 = *(const float4*)(eg + 0 * 64 + 4 * q);
            const float4 e1 = *(const float4*)(eg + 1 * 64 + 4 * q);
            const float4 e2 = *(const float4*)(eg + 2 * 64 + 4 * q);
            const float4 e3 = *(const float4*)(eg + 3 * 64 + 4 * q);
            const float4 e4 = *(const float4*)(eg + 4 * 64 + 4 * q);
            const float4 e5 = *(const float4*)(eg + 5 * 64 + 4 * q);
            const float4 e6 = *(const float4*)(eg + 6 * 64 + 4 * q);
            const float4 e7 = *(const float4*)(eg + 7 * 64 + 4 * q);
            const float xv0 = x_lds[4 * q + 0][l];
            const float xv1 = x_lds[4 * q + 1][l];
            const float xv2 = x_lds[4 * q + 2][l];
            const float xv3 = x_lds[4 * q + 3][l];
            a0 = __builtin_fmaf(xv0, e0.x, a0); a0 = __builtin_fmaf(xv1, e0.y, a0); a0 = __builtin_fmaf(xv2, e0.z, a0); a0 = __builtin_fmaf(xv3, e0.w, a0);
            a1 = __builtin_fmaf(xv0, e1.x, a1); a1 = __builtin_fmaf(xv1, e1.y, a1); a1 = __builtin_fmaf(xv2, e1.z, a1); a1 = __builtin_fmaf(xv3, e1.w, a1);
            a2 = __builtin_fmaf(xv0, e2.x, a2); a2 = __builtin_fmaf(xv1, e2.y, a2); a2 = __builtin_fmaf(xv2, e2.z, a2); a2 = __builtin_fmaf(xv3, e2.w, a2);
            a3 = __builtin_fmaf(xv0, e3.x, a3); a3 = __builtin_fmaf(xv1, e3.y, a3); a3 = __builtin_fmaf(xv2, e3.z, a3); a3 = __builtin_fmaf(xv3, e3.w, a3);
            a4 = __builtin_fmaf(xv0, e4.x, a4); a4 = __builtin_fmaf(xv1, e4.y, a4); a4 = __builtin_fmaf(xv2, e4.z, a4); a4 = __builtin_fmaf(xv3, e4.w, a4);
            a5 = __builtin_fmaf(xv0, e5.x, a5); a5 = __builtin_fmaf(xv1, e5.y, a5); a5 = __builtin_fmaf(xv2, e5.z, a5); a5 = __builtin_fmaf(xv3, e5.w, a5);
            a6 = __builtin_fmaf(xv0, e6.x, a6); a6 = __builtin_fmaf(xv1, e6.y, a6); a6 = __builtin_fmaf(xv2, e6.z, a6); a6 = __builtin_fmaf(xv3, e6.w, a6);
            a7 = __builtin_fmaf(xv0, e7.x, a7); a7 = __builtin_fmaf(xv1, e7.y, a7); a7 = __builtin_fmaf(xv2, e7.z, a7); a7 = __builtin_fmaf(xv3, e7.w, a7);
        }

        // dist = (x_sq - 2*dot) + e_sq   (same association as np; /64 exact-monotone, skipped)
        const float q0 = esq[k + 0], q1 = esq[k + 1], q2 = esq[k + 2], q3 = esq[k + 3];
        const float q4 = esq[k + 4], q5 = esq[k + 5], q6 = esq[k + 6], q7 = esq[k + 7];
        float s0 = (xsq - 2.0f * a0) + q0;
        float s1 = (xsq - 2.0f * a1) + q1;
        float s2 = (xsq - 2.0f * a2) + q2;
        float s3 = (xsq - 2.0f * a3) + q3;
        float s4 = (xsq - 2.0f * a4) + q4;
        float s5 = (xsq - 2.0f * a5) + q5;
        float s6 = (xsq - 2.0f * a6) + q6;
        float s7 = (xsq - 2.0f * a7) + q7;
        // strict < , ascending k => first-occurrence min within chunk
        if (s0 < best) { best = s0; bidx = k + 0; }
        if (s1 < best) { best = s1; bidx = k + 1; }
        if (s2 < best) { best = s2; bidx = k + 2; }
        if (s3 < best) { best = s3; bidx = k + 3; }
        if (s4 < best) { best = s4; bidx = k + 4; }
        if (s5 < best) { best = s5; bidx = k + 5; }
        if (s6 < best) { best = s6; bidx = k + 6; }
        if (s7 < best) { best = s7; bidx = k + 7; }
    }

    // merge the 8 chunk results: ascending chunk + strict '<' == global first-min
    sbest[w][l] = best;
    sidx[w][l] = bidx;
    __syncthreads();
    if (threadIdx.x < 64) {
        float bb = sbest[0][l];
        int bi = sidx[0][l];
#pragma unroll
        for (int c = 1; c < NWAVE; ++c) {
            float v = sbest[c][l];
            if (v < bb) { bb = v; bi = sidx[c][l]; }
        }
        idx_out[pix] = bi;
        out[IDX_OFF + pix] = (float)bi;   // harness reads d_out as float32
    }
}

// ---------------- gather + transpose + per-block loss partials ----------------
// block = one (b,d) plane of 1024 pixels; coalesced read/write.
__global__ void __launch_bounds__(256) gather_kernel(const float* __restrict__ x,
                                                     const float* __restrict__ e,
                                                     const int* __restrict__ idx,
                                                     float* __restrict__ out,
                                                     float* __restrict__ partial) {
    const int bd = blockIdx.x;          // = b*64 + d
    const int b = bd >> 6;
    const int d = bd & 63;
    const size_t base = (size_t)bd * 1024;
    const int* idxb = idx + b * 1024;

    float acc = 0.f;
#pragma unroll
    for (int j = 0; j < 4; ++j) {
        int p = threadIdx.x + j * 256;
        int k = idxb[p];
        float ev = e[k * 64 + d];
        float xv = x[base + p];
        out[1 + base + p] = ev;         // quantized (straight-through == codebook value)
        float df = ev - xv;
        acc = __builtin_fmaf(df, df, acc);
    }
    __shared__ float sm[256];
    sm[threadIdx.x] = acc;
    __syncthreads();
    for (int s = 128; s > 0; s >>= 1) {
        if (threadIdx.x < s) sm[threadIdx.x] += sm[threadIdx.x + s];
        __syncthreads();
    }
    if (threadIdx.x == 0) partial[bd] = sm[0];
}

// ---------------- deterministic loss finalize ----------------
__global__ void __launch_bounds__(256) loss_kernel(const float* __restrict__ partial,
                                                   float* __restrict__ out) {
    float acc = 0.f;
    for (int i = threadIdx.x; i < 4096; i += 256) acc += partial[i];
    __shared__ float sm[256];
    sm[threadIdx.x] = acc;
    __syncthreads();
    for (int s = 128; s > 0; s >>= 1) {
        if (threadIdx.x < s) sm[threadIdx.x] += sm[threadIdx.x + s];
        __syncthreads();
    }
    // loss = q_latent + 0.25*e_latent = 1.25 * mean(diff^2)
    if (threadIdx.x == 0) out[0] = sm[0] * (1.25f / 4194304.f);
}

extern "C" void kernel_launch(void* const* d_in, const int* in_sizes, int n_in,
                              void* d_out, int out_size, void* d_ws, size_t ws_size,
                              hipStream_t stream) {
    const float* x = (const float*)d_in[0];   // [64,64,32,32]
    const float* e = (const float*)d_in[1];   // [1024,64]
    float* out = (float*)d_out;

    // ws: [0,4KB) e_sq | [4KB, 4KB+256KB) idx int32 | then 16KB partials
    float* esq = (float*)d_ws;
    int* idx = (int*)((char*)d_ws + 4096);
    float* partial = (float*)((char*)d_ws + 4096 + NPIX * 4);

    esq_kernel<<<4, 256, 0, stream>>>(e, esq);
    argmin_kernel<<<NPIX / 64, 512, 0, stream>>>(x, e, esq, idx, out);
    gather_kernel<<<4096, 256, 0, stream>>>(x, e, idx, out, partial);
    loss_kernel<<<1, 256, 0, stream>>>(partial, out);
}

// Round 9
// 177.557 us; speedup vs baseline: 32.1927x; 2.7456x over previous
//
#include <hip/hip_runtime.h>

// VQ-VAE VectorQuantizer forward, fp32, MI355X.
// B=64, C=D=64, H=W=32 -> N=65536 pixels, K=1024 codes.
// Outputs (flat concat): [0] loss, [1..4194305) quantized BCHW, [4194305..) indices (as float)
//
// R9: x in LDS (R8's working x-path) + e on the SCALAR path (R4's working e-path).
// R4 post-mortem: VALUBusy 79% but 2/3 of it was xr-remat overhead (VGPR 44).
// R8 post-mortem: uniform-address VMEM e = latency-bound (6 bufs in flight).
// Now: x_lds[d][l] -> ds_read_b32, one shared vaddr + imm offsets, zero
// addressing VALU, zero remat, zero spill. e streamed as s_load batches,
// consumed as SGPR operands of v_fmac (zero VGPR writeback). 1024 blocks =
// 4 blocks/CU = 8 waves/SIMD to hide s_load latency.
// Per-code arithmetic BIT-IDENTICAL to R0-R8 (passed, absmax 3.8e-6):
// pairwise-8 x_sq (fp-contract off), sequential d-ascending fp32 FMA dot,
// dist = (x_sq - 2*dot) + e_sq, strict-< ascending-k argmin, ascending-chunk merge.

#define KCODES 1024
#define DDIM   64
#define NPIX   65536        // B*H*W
#define QELEMS 4194304      // B*C*H*W
#define IDX_OFF (1 + QELEMS)
#define NWAVE  8            // waves per block = K chunks
#define CHUNK  (KCODES / NWAVE)   // 128 codes per wave

// ---------------- e_sq precompute: replicate np.sum(e*e, axis=1) pairwise-8 ----------------
__global__ void __launch_bounds__(256) esq_kernel(const float* __restrict__ e,
                                                  float* __restrict__ esq) {
    int k = blockIdx.x * 256 + threadIdx.x;
    if (k >= KCODES) return;
    {
#pragma clang fp contract(off)
        const float* row = e + k * DDIM;
        float r[8];
#pragma unroll
        for (int j = 0; j < 8; ++j) r[j] = row[j] * row[j];
#pragma unroll
        for (int i = 1; i < 8; ++i) {
#pragma unroll
            for (int j = 0; j < 8; ++j) {
                float v = row[i * 8 + j];
                r[j] += v * v;
            }
        }
        esq[k] = ((r[0] + r[1]) + (r[2] + r[3])) + ((r[4] + r[5]) + (r[6] + r[7]));
    }
}

// ---------------- main distance + argmin kernel (K-split, x in LDS, e via s_load) ----------------
// Block = 512 threads = 8 waves; 64 pixels/block. Wave w: codes [w*128, w*128+128).
__global__ void __launch_bounds__(512) argmin_kernel(const float* __restrict__ x,
                                                     const float* __restrict__ e,
                                                     const float* __restrict__ esq,
                                                     int* __restrict__ idx_out,
                                                     float* __restrict__ out) {
    __shared__ float x_lds[DDIM][64];    // [d][l], 16KB; lane addr = l*4, d*256 imm offsets
    __shared__ float sbest[NWAVE][64];
    __shared__ int   sidx[NWAVE][64];

    const int w = __builtin_amdgcn_readfirstlane(threadIdx.x >> 6);
    const int l = threadIdx.x & 63;
    const int pix = blockIdx.x * 64 + l;     // this lane's pixel
    const int b = (blockIdx.x * 64) >> 10;   // same b for whole block (64-aligned)
    const int p0 = (blockIdx.x * 64) & 1023;

    // stage x tile: 64 d-rows x 64 px, coalesced 256B segments
    {
        const float* xg = x + (size_t)b * 65536 + p0;
        for (int t = threadIdx.x; t < DDIM * 64; t += 512)
            x_lds[t >> 6][t & 63] = xg[(size_t)(t >> 6) * 1024 + (t & 63)];
    }
    __syncthreads();

    // x_sq: EXACT numpy pairwise-8 (rounded products, no contraction), from LDS
    float xsq;
    {
#pragma clang fp contract(off)
        float r[8];
#pragma unroll
        for (int j = 0; j < 8; ++j) { float v = x_lds[j][l]; r[j] = v * v; }
#pragma unroll
        for (int ii = 1; ii < 8; ++ii) {
#pragma unroll
            for (int j = 0; j < 8; ++j) { float v = x_lds[ii * 8 + j][l]; r[j] += v * v; }
        }
        xsq = ((r[0] + r[1]) + (r[2] + r[3])) + ((r[4] + r[5]) + (r[6] + r[7]));
    }

    float best = 3.4e38f;
    int bidx = 0;
    const int kbeg = w * CHUNK;              // uniform (SGPR)

#pragma unroll 1
    for (int k = kbeg; k < kbeg + CHUNK; k += 8) {
        const float* e0 = e + (size_t)k * DDIM;   // uniform -> s_load batches
        float a0 = 0.f, a1 = 0.f, a2 = 0.f, a3 = 0.f;
        float a4 = 0.f, a5 = 0.f, a6 = 0.f, a7 = 0.f;
        // d-quads; per code the chain stays exactly d-ascending (d = 4q + j).
        // x from LDS (v-operand), e from SGPR (s-operand) -> v_fmac v, s, v.
#pragma unroll
        for (int q = 0; q < 16; ++q) {
            const float xv0 = x_lds[4 * q + 0][l];
            const float xv1 = x_lds[4 * q + 1][l];
            const float xv2 = x_lds[4 * q + 2][l];
            const float xv3 = x_lds[4 * q + 3][l];
            a0 = __builtin_fmaf(xv0, e0[0 * 64 + 4 * q + 0], a0); a0 = __builtin_fmaf(xv1, e0[0 * 64 + 4 * q + 1], a0); a0 = __builtin_fmaf(xv2, e0[0 * 64 + 4 * q + 2], a0); a0 = __builtin_fmaf(xv3, e0[0 * 64 + 4 * q + 3], a0);
            a1 = __builtin_fmaf(xv0, e0[1 * 64 + 4 * q + 0], a1); a1 = __builtin_fmaf(xv1, e0[1 * 64 + 4 * q + 1], a1); a1 = __builtin_fmaf(xv2, e0[1 * 64 + 4 * q + 2], a1); a1 = __builtin_fmaf(xv3, e0[1 * 64 + 4 * q + 3], a1);
            a2 = __builtin_fmaf(xv0, e0[2 * 64 + 4 * q + 0], a2); a2 = __builtin_fmaf(xv1, e0[2 * 64 + 4 * q + 1], a2); a2 = __builtin_fmaf(xv2, e0[2 * 64 + 4 * q + 2], a2); a2 = __builtin_fmaf(xv3, e0[2 * 64 + 4 * q + 3], a2);
            a3 = __builtin_fmaf(xv0, e0[3 * 64 + 4 * q + 0], a3); a3 = __builtin_fmaf(xv1, e0[3 * 64 + 4 * q + 1], a3); a3 = __builtin_fmaf(xv2, e0[3 * 64 + 4 * q + 2], a3); a3 = __builtin_fmaf(xv3, e0[3 * 64 + 4 * q + 3], a3);
            a4 = __builtin_fmaf(xv0, e0[4 * 64 + 4 * q + 0], a4); a4 = __builtin_fmaf(xv1, e0[4 * 64 + 4 * q + 1], a4); a4 = __builtin_fmaf(xv2, e0[4 * 64 + 4 * q + 2], a4); a4 = __builtin_fmaf(xv3, e0[4 * 64 + 4 * q + 3], a4);
            a5 = __builtin_fmaf(xv0, e0[5 * 64 + 4 * q + 0], a5); a5 = __builtin_fmaf(xv1, e0[5 * 64 + 4 * q + 1], a5); a5 = __builtin_fmaf(xv2, e0[5 * 64 + 4 * q + 2], a5); a5 = __builtin_fmaf(xv3, e0[5 * 64 + 4 * q + 3], a5);
            a6 = __builtin_fmaf(xv0, e0[6 * 64 + 4 * q + 0], a6); a6 = __builtin_fmaf(xv1, e0[6 * 64 + 4 * q + 1], a6); a6 = __builtin_fmaf(xv2, e0[6 * 64 + 4 * q + 2], a6); a6 = __builtin_fmaf(xv3, e0[6 * 64 + 4 * q + 3], a6);
            a7 = __builtin_fmaf(xv0, e0[7 * 64 + 4 * q + 0], a7); a7 = __builtin_fmaf(xv1, e0[7 * 64 + 4 * q + 1], a7); a7 = __builtin_fmaf(xv2, e0[7 * 64 + 4 * q + 2], a7); a7 = __builtin_fmaf(xv3, e0[7 * 64 + 4 * q + 3], a7);
        }

        // dist = (x_sq - 2*dot) + e_sq   (same association as np; /64 exact-monotone, skipped)
        const float q0 = esq[k + 0], q1 = esq[k + 1], q2 = esq[k + 2], q3 = esq[k + 3];
        const float q4 = esq[k + 4], q5 = esq[k + 5], q6 = esq[k + 6], q7 = esq[k + 7];
        float s0 = (xsq - 2.0f * a0) + q0;
        float s1 = (xsq - 2.0f * a1) + q1;
        float s2 = (xsq - 2.0f * a2) + q2;
        float s3 = (xsq - 2.0f * a3) + q3;
        float s4 = (xsq - 2.0f * a4) + q4;
        float s5 = (xsq - 2.0f * a5) + q5;
        float s6 = (xsq - 2.0f * a6) + q6;
        float s7 = (xsq - 2.0f * a7) + q7;
        // strict < , ascending k => first-occurrence min within chunk
        if (s0 < best) { best = s0; bidx = k + 0; }
        if (s1 < best) { best = s1; bidx = k + 1; }
        if (s2 < best) { best = s2; bidx = k + 2; }
        if (s3 < best) { best = s3; bidx = k + 3; }
        if (s4 < best) { best = s4; bidx = k + 4; }
        if (s5 < best) { best = s5; bidx = k + 5; }
        if (s6 < best) { best = s6; bidx = k + 6; }
        if (s7 < best) { best = s7; bidx = k + 7; }
    }

    // merge the 8 chunk results: ascending chunk + strict '<' == global first-min
    sbest[w][l] = best;
    sidx[w][l] = bidx;
    __syncthreads();
    if (threadIdx.x < 64) {
        float bb = sbest[0][l];
        int bi = sidx[0][l];
#pragma unroll
        for (int c = 1; c < NWAVE; ++c) {
            float v = sbest[c][l];
            if (v < bb) { bb = v; bi = sidx[c][l]; }
        }
        idx_out[pix] = bi;
        out[IDX_OFF + pix] = (float)bi;   // harness reads d_out as float32
    }
}

// ---------------- gather + transpose + per-block loss partials ----------------
// block = one (b,d) plane of 1024 pixels; coalesced read/write.
__global__ void __launch_bounds__(256) gather_kernel(const float* __restrict__ x,
                                                     const float* __restrict__ e,
                                                     const int* __restrict__ idx,
                                                     float* __restrict__ out,
                                                     float* __restrict__ partial) {
    const int bd = blockIdx.x;          // = b*64 + d
    const int b = bd >> 6;
    const int d = bd & 63;
    const size_t base = (size_t)bd * 1024;
    const int* idxb = idx + b * 1024;

    float acc = 0.f;
#pragma unroll
    for (int j = 0; j < 4; ++j) {
        int p = threadIdx.x + j * 256;
        int k = idxb[p];
        float ev = e[k * 64 + d];
        float xv = x[base + p];
        out[1 + base + p] = ev;         // quantized (straight-through == codebook value)
        float df = ev - xv;
        acc = __builtin_fmaf(df, df, acc);
    }
    __shared__ float sm[256];
    sm[threadIdx.x] = acc;
    __syncthreads();
    for (int s = 128; s > 0; s >>= 1) {
        if (threadIdx.x < s) sm[threadIdx.x] += sm[threadIdx.x + s];
        __syncthreads();
    }
    if (threadIdx.x == 0) partial[bd] = sm[0];
}

// ---------------- deterministic loss finalize ----------------
__global__ void __launch_bounds__(256) loss_kernel(const float* __restrict__ partial,
                                                   float* __restrict__ out) {
    float acc = 0.f;
    for (int i = threadIdx.x; i < 4096; i += 256) acc += partial[i];
    __shared__ float sm[256];
    sm[threadIdx.x] = acc;
    __syncthreads();
    for (int s = 128; s > 0; s >>= 1) {
        if (threadIdx.x < s) sm[threadIdx.x] += sm[threadIdx.x + s];
        __syncthreads();
    }
    // loss = q_latent + 0.25*e_latent = 1.25 * mean(diff^2)
    if (threadIdx.x == 0) out[0] = sm[0] * (1.25f / 4194304.f);
}

extern "C" void kernel_launch(void* const* d_in, const int* in_sizes, int n_in,
                              void* d_out, int out_size, void* d_ws, size_t ws_size,
                              hipStream_t stream) {
    const float* x = (const float*)d_in[0];   // [64,64,32,32]
    const float* e = (const float*)d_in[1];   // [1024,64]
    float* out = (float*)d_out;

    // ws: [0,4KB) e_sq | [4KB, 4KB+256KB) idx int32 | then 16KB partials
    float* esq = (float*)d_ws;
    int* idx = (int*)((char*)d_ws + 4096);
    float* partial = (float*)((char*)d_ws + 4096 + NPIX * 4);

    esq_kernel<<<4, 256, 0, stream>>>(e, esq);
    argmin_kernel<<<NPIX / 64, 512, 0, stream>>>(x, e, esq, idx, out);
    gather_kernel<<<4096, 256, 0, stream>>>(x, e, idx, out, partial);
    loss_kernel<<<1, 256, 0, stream>>>(partial, out);
}

// Round 10
// 145.768 us; speedup vs baseline: 39.2132x; 1.2181x over previous
//
#include <hip/hip_runtime.h>

// VQ-VAE VectorQuantizer forward, fp32, MI355X.
// B=64, C=D=64, H=W=32 -> N=65536 pixels, K=1024 codes.
// Outputs (flat concat): [0] loss, [1..4194305) quantized BCHW, [4194305..) indices (as float)
//
// R10: R9 structure (x in LDS, e on scalar path) + 2 pixels/lane.
// R9 post-mortem: R4 and R9 plateau at the same ~165us with different x-paths
// but identical e-paths -> the scalar e-stream (256MB total, ~1MB/CU) is the
// suspected wall (~110us at a few B/cyc/CU SMEM BW). Halve it: each wave's
// 32KB chunk now serves 128 pixels (2/lane). x tile 128px = 32KB LDS; no
// per-lane arrays -> no remat/spill (R6/R7 lesson). Occupancy held at
// ~4 waves/SIMD (512 blocks x 8 waves). This is the clean A/B R5 failed to
// run (R5 confounded with occupancy crash + divergent e).
// Per-code arithmetic BIT-IDENTICAL to R0-R9 (passed, absmax 3.8e-6):
// pairwise-8 x_sq (fp-contract off), sequential d-ascending fp32 FMA dot,
// dist = (x_sq - 2*dot) + e_sq, strict-< ascending-k argmin, ascending-chunk merge.

#define KCODES 1024
#define DDIM   64
#define NPIX   65536        // B*H*W
#define QELEMS 4194304      // B*C*H*W
#define IDX_OFF (1 + QELEMS)
#define NWAVE  8            // waves per block = K chunks
#define CHUNK  (KCODES / NWAVE)   // 128 codes per wave
#define PXB    128          // pixels per block (2 per lane)

// ---------------- e_sq precompute: replicate np.sum(e*e, axis=1) pairwise-8 ----------------
__global__ void __launch_bounds__(256) esq_kernel(const float* __restrict__ e,
                                                  float* __restrict__ esq) {
    int k = blockIdx.x * 256 + threadIdx.x;
    if (k >= KCODES) return;
    {
#pragma clang fp contract(off)
        const float* row = e + k * DDIM;
        float r[8];
#pragma unroll
        for (int j = 0; j < 8; ++j) r[j] = row[j] * row[j];
#pragma unroll
        for (int i = 1; i < 8; ++i) {
#pragma unroll
            for (int j = 0; j < 8; ++j) {
                float v = row[i * 8 + j];
                r[j] += v * v;
            }
        }
        esq[k] = ((r[0] + r[1]) + (r[2] + r[3])) + ((r[4] + r[5]) + (r[6] + r[7]));
    }
}

// ---------------- main distance + argmin kernel ----------------
// Block = 512 threads = 8 waves; 128 pixels/block. Wave w: codes [w*128, w*128+128)
// for all 128 pixels; lane l owns pixels blk*128+l and blk*128+l+64.
__global__ void __launch_bounds__(512) argmin_kernel(const float* __restrict__ x,
                                                     const float* __restrict__ e,
                                                     const float* __restrict__ esq,
                                                     int* __restrict__ idx_out,
                                                     float* __restrict__ out) {
    __shared__ float x_lds[DDIM][PXB];   // [d][px], 32KB; lane addrs l*4 / (l+64)*4 + d*512 imm
    __shared__ float sbest[NWAVE][PXB];
    __shared__ int   sidx[NWAVE][PXB];

    const int w = __builtin_amdgcn_readfirstlane(threadIdx.x >> 6);
    const int l = threadIdx.x & 63;
    const int pix0 = blockIdx.x * PXB + l;       // lane's first pixel
    const int b = (blockIdx.x * PXB) >> 10;      // same b for whole block (128-aligned)
    const int p0 = (blockIdx.x * PXB) & 1023;

    // stage x tile: 64 d-rows x 128 px, coalesced 512B rows
    {
        const float* xg = x + (size_t)b * 65536 + p0;
        for (int t = threadIdx.x; t < DDIM * PXB; t += 512)
            x_lds[t >> 7][t & 127] = xg[(size_t)(t >> 7) * 1024 + (t & 127)];
    }
    __syncthreads();

    // x_sq: EXACT numpy pairwise-8 (rounded products, no contraction), from LDS
    float xsq0, xsq1;
    {
#pragma clang fp contract(off)
        float r0[8], r1[8];
#pragma unroll
        for (int j = 0; j < 8; ++j) {
            float v0 = x_lds[j][l];      r0[j] = v0 * v0;
            float v1 = x_lds[j][l + 64]; r1[j] = v1 * v1;
        }
#pragma unroll
        for (int ii = 1; ii < 8; ++ii) {
#pragma unroll
            for (int j = 0; j < 8; ++j) {
                float v0 = x_lds[ii * 8 + j][l];      r0[j] += v0 * v0;
                float v1 = x_lds[ii * 8 + j][l + 64]; r1[j] += v1 * v1;
            }
        }
        xsq0 = ((r0[0] + r0[1]) + (r0[2] + r0[3])) + ((r0[4] + r0[5]) + (r0[6] + r0[7]));
        xsq1 = ((r1[0] + r1[1]) + (r1[2] + r1[3])) + ((r1[4] + r1[5]) + (r1[6] + r1[7]));
    }

    float best0 = 3.4e38f, best1 = 3.4e38f;
    int bidx0 = 0, bidx1 = 0;
    const int kbeg = w * CHUNK;              // uniform (SGPR)

#pragma unroll 1
    for (int k = kbeg; k < kbeg + CHUNK; k += 8) {
        const float* e0 = e + (size_t)k * DDIM;   // uniform -> s_load batches
        float a[8], c[8];
#pragma unroll
        for (int j = 0; j < 8; ++j) { a[j] = 0.f; c[j] = 0.f; }
        // d-quads; per code per pixel the chain stays exactly d-ascending (d = 4q + m).
        // x from LDS (v-operand), e from SGPR (s-operand).
#pragma unroll
        for (int q = 0; q < 16; ++q) {
            const float xv0 = x_lds[4 * q + 0][l];
            const float xv1 = x_lds[4 * q + 1][l];
            const float xv2 = x_lds[4 * q + 2][l];
            const float xv3 = x_lds[4 * q + 3][l];
            const float yv0 = x_lds[4 * q + 0][l + 64];
            const float yv1 = x_lds[4 * q + 1][l + 64];
            const float yv2 = x_lds[4 * q + 2][l + 64];
            const float yv3 = x_lds[4 * q + 3][l + 64];
#pragma unroll
            for (int j = 0; j < 8; ++j) {
                const float e_0 = e0[j * 64 + 4 * q + 0];
                const float e_1 = e0[j * 64 + 4 * q + 1];
                const float e_2 = e0[j * 64 + 4 * q + 2];
                const float e_3 = e0[j * 64 + 4 * q + 3];
                a[j] = __builtin_fmaf(xv0, e_0, a[j]);
                a[j] = __builtin_fmaf(xv1, e_1, a[j]);
                a[j] = __builtin_fmaf(xv2, e_2, a[j]);
                a[j] = __builtin_fmaf(xv3, e_3, a[j]);
                c[j] = __builtin_fmaf(yv0, e_0, c[j]);
                c[j] = __builtin_fmaf(yv1, e_1, c[j]);
                c[j] = __builtin_fmaf(yv2, e_2, c[j]);
                c[j] = __builtin_fmaf(yv3, e_3, c[j]);
            }
        }

        // dist = (x_sq - 2*dot) + e_sq; strict < , ascending k (per pixel independently)
#pragma unroll
        for (int j = 0; j < 8; ++j) {
            const float qj = esq[k + j];
            const float s = (xsq0 - 2.0f * a[j]) + qj;
            if (s < best0) { best0 = s; bidx0 = k + j; }
            const float t = (xsq1 - 2.0f * c[j]) + qj;
            if (t < best1) { best1 = t; bidx1 = k + j; }
        }
    }

    // merge the 8 chunk results: ascending chunk + strict '<' == global first-min
    sbest[w][l] = best0;        sbest[w][l + 64] = best1;
    sidx[w][l] = bidx0;         sidx[w][l + 64] = bidx1;
    __syncthreads();
    if (threadIdx.x < PXB) {
        const int t = threadIdx.x;
        float bb = sbest[0][t];
        int bi = sidx[0][t];
#pragma unroll
        for (int c2 = 1; c2 < NWAVE; ++c2) {
            float v = sbest[c2][t];
            if (v < bb) { bb = v; bi = sidx[c2][t]; }
        }
        const int gi = blockIdx.x * PXB + t;
        idx_out[gi] = bi;
        out[IDX_OFF + gi] = (float)bi;   // harness reads d_out as float32
    }
}

// ---------------- gather + transpose + per-block loss partials ----------------
// block = one (b,d) plane of 1024 pixels; coalesced read/write.
__global__ void __launch_bounds__(256) gather_kernel(const float* __restrict__ x,
                                                     const float* __restrict__ e,
                                                     const int* __restrict__ idx,
                                                     float* __restrict__ out,
                                                     float* __restrict__ partial) {
    const int bd = blockIdx.x;          // = b*64 + d
    const int b = bd >> 6;
    const int d = bd & 63;
    const size_t base = (size_t)bd * 1024;
    const int* idxb = idx + b * 1024;

    float acc = 0.f;
#pragma unroll
    for (int j = 0; j < 4; ++j) {
        int p = threadIdx.x + j * 256;
        int k = idxb[p];
        float ev = e[k * 64 + d];
        float xv = x[base + p];
        out[1 + base + p] = ev;         // quantized (straight-through == codebook value)
        float df = ev - xv;
        acc = __builtin_fmaf(df, df, acc);
    }
    __shared__ float sm[256];
    sm[threadIdx.x] = acc;
    __syncthreads();
    for (int s = 128; s > 0; s >>= 1) {
        if (threadIdx.x < s) sm[threadIdx.x] += sm[threadIdx.x + s];
        __syncthreads();
    }
    if (threadIdx.x == 0) partial[bd] = sm[0];
}

// ---------------- deterministic loss finalize ----------------
__global__ void __launch_bounds__(256) loss_kernel(const float* __restrict__ partial,
                                                   float* __restrict__ out) {
    float acc = 0.f;
    for (int i = threadIdx.x; i < 4096; i += 256) acc += partial[i];
    __shared__ float sm[256];
    sm[threadIdx.x] = acc;
    __syncthreads();
    for (int s = 128; s > 0; s >>= 1) {
        if (threadIdx.x < s) sm[threadIdx.x] += sm[threadIdx.x + s];
        __syncthreads();
    }
    // loss = q_latent + 0.25*e_latent = 1.25 * mean(diff^2)
    if (threadIdx.x == 0) out[0] = sm[0] * (1.25f / 4194304.f);
}

extern "C" void kernel_launch(void* const* d_in, const int* in_sizes, int n_in,
                              void* d_out, int out_size, void* d_ws, size_t ws_size,
                              hipStream_t stream) {
    const float* x = (const float*)d_in[0];   // [64,64,32,32]
    const float* e = (const float*)d_in[1];   // [1024,64]
    float* out = (float*)d_out;

    // ws: [0,4KB) e_sq | [4KB, 4KB+256KB) idx int32 | then 16KB partials
    float* esq = (float*)d_ws;
    int* idx = (int*)((char*)d_ws + 4096);
    float* partial = (float*)((char*)d_ws + 4096 + NPIX * 4);

    esq_kernel<<<4, 256, 0, stream>>>(e, esq);
    argmin_kernel<<<NPIX / PXB, 512, 0, stream>>>(x, e, esq, idx, out);
    gather_kernel<<<4096, 256, 0, stream>>>(x, e, idx, out, partial);
    loss_kernel<<<1, 256, 0, stream>>>(partial, out);
}